// Round 7
// baseline (155.557 us; speedup 1.0000x reference)
//
#include <hip/hip_runtime.h>
#include <stdint.h>

#define D_MODEL 768
#define E3      2304
#define NCTX    2048
#define NH      12
#define HD      64
#define MROWS   4096  // 2*2048
#define NHTOT   24    // 2*12

typedef __attribute__((ext_vector_type(8))) short short8;   // 8 bf16 — MFMA x32 A/B frag
typedef __attribute__((ext_vector_type(4))) short bf16x4;   // 4 bf16 — MFMA x16 A/B frag
typedef __attribute__((ext_vector_type(4))) float f32x4;    // MFMA C/D frag

typedef __attribute__((address_space(3))) uint32_t lds_u32;
typedef __attribute__((address_space(1))) uint32_t glob_u32;

__device__ __forceinline__ void async_copy16(const void* g, void* l) {
    __builtin_amdgcn_global_load_lds((const glob_u32*)(uintptr_t)g,
                                     (lds_u32*)(uint32_t)(uintptr_t)l, 16, 0, 0);
}

__device__ __forceinline__ unsigned short f2bf(float f) {  // RNE fp32->bf16
    uint32_t u = __builtin_bit_cast(uint32_t, f);
    u += 0x7fffu + ((u >> 16) & 1u);
    return (unsigned short)(u >> 16);
}

__device__ __forceinline__ float fast_exp2(float x) {
#if __has_builtin(__builtin_amdgcn_exp2f)
    return __builtin_amdgcn_exp2f(x);
#else
    return __expf(x * 0.6931471805599453f);
#endif
}

// x16 bf16 MFMA: device pass has the builtin (r6 evidence: only the HOST pass
// lacked it). Host stub just needs to parse — device code never runs on host.
__device__ __forceinline__ f32x4 mfma16_bf16(bf16x4 a, bf16x4 b, f32x4 c) {
#if defined(__HIP_DEVICE_COMPILE__)
    return __builtin_amdgcn_mfma_f32_16x16x16bf16_1k(a, b, c, 0, 0, 0);
#else
    (void)a; (void)b;
    return c;
#endif
}

// ---------------- cast fp32 -> bf16 ----------------
__global__ void cast_bf16_kernel(const float* __restrict__ in, unsigned short* __restrict__ out) {
    int i = blockIdx.x * blockDim.x + threadIdx.x;
    float4 v = ((const float4*)in)[i];
    ushort4 o;
    o.x = f2bf(v.x); o.y = f2bf(v.y); o.z = f2bf(v.z); o.w = f2bf(v.w);
    ((ushort4*)out)[i] = o;
}

// ---------------- QKV GEMM: 128x96 tiles, BK=64, k-major conflict-free LDS ----------------
// LDS layout: elem(row R, col k) = (R>>3)*512 + (k>>3)*64 + (R&7)*8 + (k&7)
//  -> lane-linear for global_load_lds (1 region = 8 rows x 64 cols = 1 KB)
//  -> frag ds_read_b128 spreads over all 32 banks at 8 words/bank (the wave64 floor)
// Grid (24, 32) = 768 blocks = exactly 3/CU.
__global__ __launch_bounds__(256) void qkv_gemm(const unsigned short* __restrict__ A,
                                                const unsigned short* __restrict__ B,
                                                const float* __restrict__ bias,
                                                unsigned short* __restrict__ Zq,
                                                unsigned short* __restrict__ Kb,
                                                unsigned short* __restrict__ Vb) {
    __shared__ __attribute__((aligned(16))) unsigned short sA[128 * 64];
    __shared__ __attribute__((aligned(16))) unsigned short sB[96 * 64];

    const int tid  = threadIdx.x;
    const int wave = tid >> 6;
    const int lane = tid & 63;
    const int quad = lane >> 4;
    const int l15  = lane & 15;
    const int wm   = (wave >> 1) * 64;   // 0 or 64
    const int wn   = (wave & 1) * 48;    // 0 or 48
    const int row0 = blockIdx.y * 128;
    const int col0 = blockIdx.x * 96;

    const int srow   = lane & 7;         // row within 8-row region
    const int schunk = (lane >> 3) * 8;  // 8-elem k-chunk

    f32x4 acc[4][3] = {};

    for (int k0 = 0; k0 < D_MODEL; k0 += 64) {
        __syncthreads();
#pragma unroll
        for (int c = 0; c < 4; ++c) {    // A: 16 regions, 4 per wave
            const int reg = wave * 4 + c;
            async_copy16(A + (size_t)(row0 + reg * 8 + srow) * D_MODEL + k0 + schunk, &sA[reg * 512]);
        }
#pragma unroll
        for (int c = 0; c < 3; ++c) {    // B: 12 regions, 3 per wave
            const int reg = wave * 3 + c;
            async_copy16(B + (size_t)(col0 + reg * 8 + srow) * D_MODEL + k0 + schunk, &sB[reg * 512]);
        }
        __syncthreads();

#pragma unroll
        for (int ks = 0; ks < 2; ++ks) {
            const int qoff = (ks * 4 + quad) * 64 + (l15 & 7) * 8;
            short8 aF[4], bF[3];
#pragma unroll
            for (int i = 0; i < 4; ++i)
                aF[i] = *(const short8*)&sA[((wm >> 3) + i * 2 + (l15 >> 3)) * 512 + qoff];
#pragma unroll
            for (int j = 0; j < 3; ++j)
                bF[j] = *(const short8*)&sB[((wn >> 3) + j * 2 + (l15 >> 3)) * 512 + qoff];
#pragma unroll
            for (int i = 0; i < 4; ++i)
#pragma unroll
                for (int j = 0; j < 3; ++j)
                    acc[i][j] = __builtin_amdgcn_mfma_f32_16x16x32_bf16(aF[i], bF[j], acc[i][j], 0, 0, 0);
        }
    }

    // epilogue: C/D layout col=l15 (j dim), row=quad*4+reg (i dim)
    if (col0 < D_MODEL) {
        // ---- K -> Kb blocked: per (nh,kb): (((ks*4+ct)*4+quadd)*16 + key%16)*8 + e ----
#pragma unroll
        for (int j = 0; j < 3; ++j) {
            const int col = col0 + wn + j * 16 + l15;
            const float bv = bias[col];
            const int h = col >> 6, d = col & 63;
            const int ks = d >> 5, quadd = (d >> 3) & 3, e = d & 7;
#pragma unroll
            for (int i = 0; i < 4; ++i) {
                const int row = row0 + wm + i * 16 + quad * 4;
                const int n = row >> 11;
                const int key = row & (NCTX - 1);
                const int kb = key >> 6;
                const int ct = (key >> 4) & 3;
                const size_t base = ((size_t)((n * NH + h) * 32 + kb)) * 4096
                                  + (((ks * 4 + ct) * 4 + quadd) * 16) * 8 + e;
#pragma unroll
                for (int r = 0; r < 4; ++r)
                    Kb[base + (size_t)(quad * 4 + r) * 8] = f2bf(acc[i][j][r] + bv);
            }
        }
    } else if (col0 < 2 * D_MODEL) {
        // ---- Q -> Zq (scaled by log2e/sqrt(768)) ----
        const float zscale = 0.036084391824351615f * 1.4426950408889634f;
#pragma unroll
        for (int j = 0; j < 3; ++j) {
            const int colz = col0 + wn + j * 16 + l15;
            const float bv = bias[colz];
            const int col = colz - D_MODEL;
#pragma unroll
            for (int i = 0; i < 4; ++i) {
                const int row = row0 + wm + i * 16 + quad * 4;
#pragma unroll
                for (int r = 0; r < 4; ++r)
                    Zq[(size_t)(row + r) * D_MODEL + col] = f2bf((acc[i][j][r] + bv) * zscale);
            }
        }
    } else {
        // ---- V -> Vb blocked: per (nh,kb): (((ct*4+dt)*4+quadv)*16 + l15d)*4 + key%4 ----
#pragma unroll
        for (int j = 0; j < 3; ++j) {
            const int col = col0 + wn + j * 16 + l15;
            const float bv = bias[col];
            const int ch = col - 2 * D_MODEL;
            const int h = ch >> 6, d = ch & 63;
            const int dt = d >> 4, l15d = d & 15;
#pragma unroll
            for (int i = 0; i < 4; ++i) {
                const int row = row0 + wm + i * 16 + quad * 4;    // key base, %4==0
                const int n = row >> 11;
                const int key = row & (NCTX - 1);
                const int kb = key >> 6;
                const int ct = (key >> 4) & 3;
                ushort4 w4;
                w4.x = f2bf(acc[i][j][0] + bv);
                w4.y = f2bf(acc[i][j][1] + bv);
                w4.z = f2bf(acc[i][j][2] + bv);
                w4.w = f2bf(acc[i][j][3] + bv);
                *(ushort4*)&Vb[((size_t)((n * NH + h) * 32 + kb)) * 4096
                               + (((ct * 4 + dt) * 4 + quad) * 16 + l15d) * 4] = w4;
            }
        }
    }
}

// ---------------- flash attention: K via LDS (dbuf), V direct-global, XCD-swizzled ----------------
// Block = 4 waves = one q64-tile t of one (n,h); wave w owns q16 [t*64+w*16, +16).
// nh = (b%8)*3 + (b/8)%3 pins each head's K/V (1 MB) to one XCD L2 (3 heads = 3 MB).
// Barrier drains only 8 KB K staging; V dwordx2 loads are wave-local, hidden under QK+exp.
__global__ __launch_bounds__(256) void attn_kernel(const unsigned short* __restrict__ Zq,
                                                   const unsigned short* __restrict__ Kb,
                                                   const unsigned short* __restrict__ Vb,
                                                   float* __restrict__ out) {
    __shared__ __attribute__((aligned(16))) unsigned short sK[2][4096];

    const int tid  = threadIdx.x;
    const int wave = tid >> 6;
    const int lane = tid & 63;
    const int quad = lane >> 4;
    const int l15  = lane & 15;
    const int b    = blockIdx.x;
    const int nh   = (b & 7) * 3 + ((b >> 3) % 3);   // same nh -> same XCD (round-robin heuristic)
    const int t    = (NCTX / 64 - 1) - b / NHTOT;    // heavy-first
    const int n    = nh / NH;
    const int h    = nh - n * NH;

    const unsigned short* KbP = Kb + (size_t)(nh * 32) * 4096;
    const unsigned short* VbP = Vb + (size_t)(nh * 32) * 4096;

    // Q B-frags: lane holds Q[q = t*64+wave*16+l15][d = ks*32+quad*8..+7]
    const unsigned short* Qp = Zq + (size_t)(n * NCTX + t * 64 + wave * 16) * D_MODEL + h * HD;
    short8 qf[2];
#pragma unroll
    for (int ks = 0; ks < 2; ++ks)
        qf[ks] = *(const short8*)&Qp[(size_t)l15 * D_MODEL + ks * 32 + quad * 8];

    f32x4 o[4] = {};   // [dt]: O[q=quad*4+r][d=dt*16+l15]
    float lsum = 0.0f; // partial row-sum for q=l15

    // prologue: stage K(kb=0); 8 KB / 4 waves = 2 instrs/wave
#pragma unroll
    for (int c = 0; c < 2; ++c) {
        const int off = wave * 1024 + c * 512;
        async_copy16(KbP + off + lane * 8, &sK[0][off]);
    }

    for (int kb = 0; kb <= t; ++kb) {
        const int buf = kb & 1;
        __syncthreads();                               // drains K staging of kb; frees buf^1
        if (kb < t) {
#pragma unroll
            for (int c = 0; c < 2; ++c) {
                const int off = wave * 1024 + c * 512;
                async_copy16(KbP + (size_t)(kb + 1) * 4096 + off + lane * 8, &sK[buf ^ 1][off]);
            }
        }

        // V frags direct from global (lane-linear blocked layout; latency hides under QK+exp)
        bf16x4 vf[4][4];
#pragma unroll
        for (int ct = 0; ct < 4; ++ct)
#pragma unroll
            for (int dt = 0; dt < 4; ++dt)
                vf[ct][dt] = *(const bf16x4*)&VbP[(size_t)kb * 4096 + (ct * 4 + dt) * 256 + lane * 4];

        // K A-frags from LDS (conflict-free lane-linear)
        short8 kf[2][4];
#pragma unroll
        for (int ks = 0; ks < 2; ++ks)
#pragma unroll
            for (int ct = 0; ct < 4; ++ct)
                kf[ks][ct] = *(const short8*)&sK[buf][(ks * 4 + ct) * 512 + lane * 8];

        // S^T = K Q^T: lane holds S[q=l15][key = kb*64 + ct*16 + quad*4 + r]
        f32x4 s[4] = {};
#pragma unroll
        for (int ct = 0; ct < 4; ++ct) {
            s[ct] = __builtin_amdgcn_mfma_f32_16x16x32_bf16(kf[0][ct], qf[0], s[ct], 0, 0, 0);
            s[ct] = __builtin_amdgcn_mfma_f32_16x16x32_bf16(kf[1][ct], qf[1], s[ct], 0, 0, 0);
        }

        const bool diag = (kb == t);
        const int qg = t * 64 + wave * 16 + l15;
        bf16x4 pA[4];
#pragma unroll
        for (int ct = 0; ct < 4; ++ct) {
            float pv[4];
#pragma unroll
            for (int r = 0; r < 4; ++r) {
                const int key = kb * 64 + ct * 16 + quad * 4 + r;
                float sv = s[ct][r];
                if (diag && key > qg) sv = -INFINITY;
                pv[r] = fast_exp2(sv);
                lsum += pv[r];
            }
            pA[ct][0] = (short)f2bf(pv[0]); pA[ct][1] = (short)f2bf(pv[1]);
            pA[ct][2] = (short)f2bf(pv[2]); pA[ct][3] = (short)f2bf(pv[3]);
        }

        // O += P V (x16 MFMA; P already in A-layout in registers)
#pragma unroll
        for (int ct = 0; ct < 4; ++ct)
#pragma unroll
            for (int dt = 0; dt < 4; ++dt)
                o[dt] = mfma16_bf16(pA[ct], vf[ct][dt], o[dt]);
    }

    // epilogue: full row-sum for q=l15 (reduce across quads), normalize, store
    float l = lsum;
    l += __shfl_xor(l, 16);
    l += __shfl_xor(l, 32);
    const float linv = 1.0f / l;                      // valid for q=l15
#pragma unroll
    for (int r = 0; r < 4; ++r) {
        const float inv = __shfl(linv, quad * 4 + r); // source lane's l15 == output q row
        const size_t row = (size_t)n * NCTX + t * 64 + wave * 16 + quad * 4 + r;
#pragma unroll
        for (int dt = 0; dt < 4; ++dt)
            out[row * D_MODEL + h * HD + dt * 16 + l15] = o[dt][r] * inv;
    }
}

extern "C" void kernel_launch(void* const* d_in, const int* in_sizes, int n_in,
                              void* d_out, int out_size, void* d_ws, size_t ws_size,
                              hipStream_t stream) {
    const float* x = (const float*)d_in[0];   // [2,2048,768]
    const float* W = (const float*)d_in[1];   // [2304,768]
    const float* b = (const float*)d_in[2];   // [2304]
    float* out = (float*)d_out;

    unsigned short* xb = (unsigned short*)d_ws;                    // 4096*768
    unsigned short* Wb = xb + (size_t)MROWS * D_MODEL;             // 2304*768
    unsigned short* Zq = Wb + (size_t)E3 * D_MODEL;                // 4096*768 (Q only)
    unsigned short* Kb = Zq + (size_t)MROWS * D_MODEL;             // 24*32*4096
    unsigned short* Vb = Kb + (size_t)NHTOT * 32 * 4096;           // 24*32*4096

    cast_bf16_kernel<<<dim3((MROWS * D_MODEL / 4) / 256), 256, 0, stream>>>(x, xb);
    cast_bf16_kernel<<<dim3((E3 * D_MODEL / 4) / 256), 256, 0, stream>>>(W, Wb);
    qkv_gemm<<<dim3(E3 / 96, MROWS / 128), 256, 0, stream>>>(xb, Wb, b, Zq, Kb, Vb);
    attn_kernel<<<dim3(NHTOT * (NCTX / 64)), 256, 0, stream>>>(Zq, Kb, Vb, out);
}

// Round 8
// 148.502 us; speedup vs baseline: 1.0475x; 1.0475x over previous
//
#include <hip/hip_runtime.h>
#include <stdint.h>

#define D_MODEL 768
#define E3      2304
#define NCTX    2048
#define NH      12
#define HD      64
#define MROWS   4096  // 2*2048
#define NHTOT   24    // 2*12

typedef __attribute__((ext_vector_type(8))) short short8;   // 8 bf16 — MFMA x32 A/B frag
typedef __attribute__((ext_vector_type(4))) short bf16x4;   // 4 bf16 — MFMA x16 A/B frag
typedef __attribute__((ext_vector_type(4))) float f32x4;    // MFMA C/D frag

typedef __attribute__((address_space(3))) uint32_t lds_u32;
typedef __attribute__((address_space(1))) uint32_t glob_u32;

__device__ __forceinline__ void async_copy16(const void* g, void* l) {
    __builtin_amdgcn_global_load_lds((const glob_u32*)(uintptr_t)g,
                                     (lds_u32*)(uint32_t)(uintptr_t)l, 16, 0, 0);
}

__device__ __forceinline__ unsigned short f2bf(float f) {  // RNE fp32->bf16
    uint32_t u = __builtin_bit_cast(uint32_t, f);
    u += 0x7fffu + ((u >> 16) & 1u);
    return (unsigned short)(u >> 16);
}

__device__ __forceinline__ float fast_exp2(float x) {
#if __has_builtin(__builtin_amdgcn_exp2f)
    return __builtin_amdgcn_exp2f(x);
#else
    return __expf(x * 0.6931471805599453f);
#endif
}

// x16 bf16 MFMA: device pass has the builtin; host pass lacks it (r6) — stub for parse.
__device__ __forceinline__ f32x4 mfma16_bf16(bf16x4 a, bf16x4 b, f32x4 c) {
#if defined(__HIP_DEVICE_COMPILE__)
    return __builtin_amdgcn_mfma_f32_16x16x16bf16_1k(a, b, c, 0, 0, 0);
#else
    (void)a; (void)b;
    return c;
#endif
}

// Raw barrier that waits ONLY lgkmcnt(0) — leaves global (vmcnt) prefetch loads
// in flight across the barrier. simm16 0xC07F = vmcnt(63) expcnt(7) lgkmcnt(0).
__device__ __forceinline__ void barrier_lgkm() {
#if defined(__HIP_DEVICE_COMPILE__)
    asm volatile("" ::: "memory");
    __builtin_amdgcn_s_waitcnt(0xC07F);
    __builtin_amdgcn_s_barrier();
    asm volatile("" ::: "memory");
#endif
}

// ---------------- cast fp32 -> bf16 ----------------
__global__ void cast_bf16_kernel(const float* __restrict__ in, unsigned short* __restrict__ out) {
    int i = blockIdx.x * blockDim.x + threadIdx.x;
    float4 v = ((const float4*)in)[i];
    ushort4 o;
    o.x = f2bf(v.x); o.y = f2bf(v.y); o.z = f2bf(v.z); o.w = f2bf(v.w);
    ((ushort4*)out)[i] = o;
}

// ---------------- QKV GEMM: 128x96, BK=64, register-prefetch pipeline ----------------
// k-major LDS layout (r7, conflict-free): elem(R,k) = (R>>3)*512 + (k>>3)*64 + (R&7)*8 + (k&7)
// Pipeline per iter: barrier(lgkm) -> issue global loads k+1 (regs) -> ds_read frags
//   -> barrier(lgkm) -> MFMA  ||  vmcnt-wait + ds_write k+1.
// Raw lgkm-only barriers keep prefetch vmcnt in flight (no per-iter HBM/L2 latency drain).
__global__ __launch_bounds__(256) void qkv_gemm(const unsigned short* __restrict__ A,
                                                const unsigned short* __restrict__ B,
                                                const float* __restrict__ bias,
                                                unsigned short* __restrict__ Zq,
                                                unsigned short* __restrict__ Kb,
                                                unsigned short* __restrict__ Vb) {
    __shared__ __attribute__((aligned(16))) unsigned short sA[128 * 64];
    __shared__ __attribute__((aligned(16))) unsigned short sB[96 * 64];

    const int tid  = threadIdx.x;
    const int wave = tid >> 6;
    const int lane = tid & 63;
    const int quad = lane >> 4;
    const int l15  = lane & 15;
    const int wm   = (wave >> 1) * 64;   // 0 or 64
    const int wn   = (wave & 1) * 48;    // 0 or 48
    const int row0 = blockIdx.y * 128;
    const int col0 = blockIdx.x * 96;

    const int srow   = lane & 7;         // row within 8-row region
    const int schunk = (lane >> 3) * 8;  // 8-elem k-chunk

    // per-wave global source pointers (k0 added per iteration)
    const unsigned short* gA[4];
    const unsigned short* gB[3];
#pragma unroll
    for (int c = 0; c < 4; ++c)
        gA[c] = A + (size_t)(row0 + (wave * 4 + c) * 8 + srow) * D_MODEL + schunk;
#pragma unroll
    for (int c = 0; c < 3; ++c)
        gB[c] = B + (size_t)(col0 + (wave * 3 + c) * 8 + srow) * D_MODEL + schunk;

    // LDS destinations (lane-linear within each 1 KB region)
    unsigned short* const dA = &sA[(wave * 4) * 512 + lane * 8];
    unsigned short* const dB = &sB[(wave * 3) * 512 + lane * 8];

    short8 ra[4], rb[3];

    // prologue: load tile 0 -> regs -> LDS
#pragma unroll
    for (int c = 0; c < 4; ++c) ra[c] = *(const short8*)(gA[c]);
#pragma unroll
    for (int c = 0; c < 3; ++c) rb[c] = *(const short8*)(gB[c]);
#pragma unroll
    for (int c = 0; c < 4; ++c) *(short8*)(dA + c * 512) = ra[c];
#pragma unroll
    for (int c = 0; c < 3; ++c) *(short8*)(dB + c * 512) = rb[c];

    f32x4 acc[4][3] = {};

    for (int k0 = 0; k0 < D_MODEL; k0 += 64) {
        barrier_lgkm();                 // tile k0 ds_writes visible to all waves

        const bool more = (k0 + 64 < D_MODEL);
        if (more) {                     // issue prefetch of tile k0+64 (latency hidden below)
#pragma unroll
            for (int c = 0; c < 4; ++c) ra[c] = *(const short8*)(gA[c] + k0 + 64);
#pragma unroll
            for (int c = 0; c < 3; ++c) rb[c] = *(const short8*)(gB[c] + k0 + 64);
        }

        // frag reads (all 14 b128 before barrier B — single LDS buffer)
        short8 aF[2][4], bF[2][3];
#pragma unroll
        for (int ks = 0; ks < 2; ++ks) {
            const int qoff = (ks * 4 + quad) * 64 + (l15 & 7) * 8;
#pragma unroll
            for (int i = 0; i < 4; ++i)
                aF[ks][i] = *(const short8*)&sA[((wm >> 3) + i * 2 + (l15 >> 3)) * 512 + qoff];
#pragma unroll
            for (int j = 0; j < 3; ++j)
                bF[ks][j] = *(const short8*)&sB[((wn >> 3) + j * 2 + (l15 >> 3)) * 512 + qoff];
        }

        barrier_lgkm();                 // all waves' frag reads done -> LDS reusable

#pragma unroll
        for (int ks = 0; ks < 2; ++ks)
#pragma unroll
            for (int i = 0; i < 4; ++i)
#pragma unroll
                for (int j = 0; j < 3; ++j)
                    acc[i][j] = __builtin_amdgcn_mfma_f32_16x16x32_bf16(aF[ks][i], bF[ks][j], acc[i][j], 0, 0, 0);

        if (more) {                     // vmcnt wait lands here, after a full compute stage
#pragma unroll
            for (int c = 0; c < 4; ++c) *(short8*)(dA + c * 512) = ra[c];
#pragma unroll
            for (int c = 0; c < 3; ++c) *(short8*)(dB + c * 512) = rb[c];
        }
    }

    // epilogue: C/D layout col=l15 (j dim), row=quad*4+reg (i dim)
    if (col0 < D_MODEL) {
        // ---- K -> Kb blocked: per (nh,kb): (((ks*4+ct)*4+quadd)*16 + key%16)*8 + e ----
#pragma unroll
        for (int j = 0; j < 3; ++j) {
            const int col = col0 + wn + j * 16 + l15;
            const float bv = bias[col];
            const int h = col >> 6, d = col & 63;
            const int ks = d >> 5, quadd = (d >> 3) & 3, e = d & 7;
#pragma unroll
            for (int i = 0; i < 4; ++i) {
                const int row = row0 + wm + i * 16 + quad * 4;
                const int n = row >> 11;
                const int key = row & (NCTX - 1);
                const int kb = key >> 6;
                const int ct = (key >> 4) & 3;
                const size_t base = ((size_t)((n * NH + h) * 32 + kb)) * 4096
                                  + (((ks * 4 + ct) * 4 + quadd) * 16) * 8 + e;
#pragma unroll
                for (int r = 0; r < 4; ++r)
                    Kb[base + (size_t)(quad * 4 + r) * 8] = f2bf(acc[i][j][r] + bv);
            }
        }
    } else if (col0 < 2 * D_MODEL) {
        // ---- Q -> Zq (scaled by log2e/sqrt(768)) ----
        const float zscale = 0.036084391824351615f * 1.4426950408889634f;
#pragma unroll
        for (int j = 0; j < 3; ++j) {
            const int colz = col0 + wn + j * 16 + l15;
            const float bv = bias[colz];
            const int col = colz - D_MODEL;
#pragma unroll
            for (int i = 0; i < 4; ++i) {
                const int row = row0 + wm + i * 16 + quad * 4;
#pragma unroll
                for (int r = 0; r < 4; ++r)
                    Zq[(size_t)(row + r) * D_MODEL + col] = f2bf((acc[i][j][r] + bv) * zscale);
            }
        }
    } else {
        // ---- V -> Vb blocked: per (nh,kb): (((ct*4+dt)*4+quadv)*16 + l15d)*4 + key%4 ----
#pragma unroll
        for (int j = 0; j < 3; ++j) {
            const int col = col0 + wn + j * 16 + l15;
            const float bv = bias[col];
            const int ch = col - 2 * D_MODEL;
            const int h = ch >> 6, d = ch & 63;
            const int dt = d >> 4, l15d = d & 15;
#pragma unroll
            for (int i = 0; i < 4; ++i) {
                const int row = row0 + wm + i * 16 + quad * 4;    // key base, %4==0
                const int n = row >> 11;
                const int key = row & (NCTX - 1);
                const int kb = key >> 6;
                const int ct = (key >> 4) & 3;
                ushort4 w4;
                w4.x = f2bf(acc[i][j][0] + bv);
                w4.y = f2bf(acc[i][j][1] + bv);
                w4.z = f2bf(acc[i][j][2] + bv);
                w4.w = f2bf(acc[i][j][3] + bv);
                *(ushort4*)&Vb[((size_t)((n * NH + h) * 32 + kb)) * 4096
                               + (((ct * 4 + dt) * 4 + quad) * 16 + l15d) * 4] = w4;
            }
        }
    }
}

// ---------------- flash attention: r5 configuration (measured ~44 µs) ----------------
// Block = 4 waves = one q64-tile t of one (n,h); wave w owns q16 [t*64+w*16, +16).
// K AND V staged to LDS via global_load_lds (shared across 4 waves — r7's V-direct
// quadrupled V traffic, reverted). Double-buffered, one __syncthreads per key-block.
// S^T = K*Q^T keeps P in x16-MFMA A-layout in registers. m fixed 0; l deferred.
__global__ __launch_bounds__(256) void attn_kernel(const unsigned short* __restrict__ Zq,
                                                   const unsigned short* __restrict__ Kb,
                                                   const unsigned short* __restrict__ Vb,
                                                   float* __restrict__ out) {
    __shared__ __attribute__((aligned(16))) unsigned short sK[2][4096];
    __shared__ __attribute__((aligned(16))) unsigned short sV[2][4096];

    const int tid  = threadIdx.x;
    const int wave = tid >> 6;
    const int lane = tid & 63;
    const int quad = lane >> 4;
    const int l15  = lane & 15;
    const int b    = blockIdx.x;
    const int nh   = b % NHTOT;
    const int t    = (NCTX / 64 - 1) - b / NHTOT;    // heavy-first
    const int n    = nh / NH;
    const int h    = nh - n * NH;

    const unsigned short* KbP = Kb + (size_t)(nh * 32) * 4096;
    const unsigned short* VbP = Vb + (size_t)(nh * 32) * 4096;

    // Q B-frags: lane holds Q[q = t*64+wave*16+l15][d = ks*32+quad*8..+7]
    const unsigned short* Qp = Zq + (size_t)(n * NCTX + t * 64 + wave * 16) * D_MODEL + h * HD;
    short8 qf[2];
#pragma unroll
    for (int ks = 0; ks < 2; ++ks)
        qf[ks] = *(const short8*)&Qp[(size_t)l15 * D_MODEL + ks * 32 + quad * 8];

    f32x4 o[4] = {};   // [dt]: O[q=quad*4+r][d=dt*16+l15]
    float lsum = 0.0f; // partial row-sum for q=l15

    // prologue: stage K+V (kb=0); 16 KB / 4 waves = 4 instrs/wave
#pragma unroll
    for (int c = 0; c < 2; ++c) {
        const int off = wave * 1024 + c * 512;
        async_copy16(KbP + off + lane * 8, &sK[0][off]);
        async_copy16(VbP + off + lane * 8, &sV[0][off]);
    }

    for (int kb = 0; kb <= t; ++kb) {
        const int buf = kb & 1;
        __syncthreads();                               // drains staging of kb; frees buf^1
        if (kb < t) {
#pragma unroll
            for (int c = 0; c < 2; ++c) {
                const int off = wave * 1024 + c * 512;
                async_copy16(KbP + (size_t)(kb + 1) * 4096 + off + lane * 8, &sK[buf ^ 1][off]);
                async_copy16(VbP + (size_t)(kb + 1) * 4096 + off + lane * 8, &sV[buf ^ 1][off]);
            }
        }

        // K A-frags from LDS (lane-linear, conflict-free)
        short8 kf[2][4];
#pragma unroll
        for (int ks = 0; ks < 2; ++ks)
#pragma unroll
            for (int ct = 0; ct < 4; ++ct)
                kf[ks][ct] = *(const short8*)&sK[buf][(ks * 4 + ct) * 512 + lane * 8];

        // S^T = K Q^T: lane holds S[q=l15][key = kb*64 + ct*16 + quad*4 + r]
        f32x4 s[4] = {};
#pragma unroll
        for (int ct = 0; ct < 4; ++ct) {
            s[ct] = __builtin_amdgcn_mfma_f32_16x16x32_bf16(kf[0][ct], qf[0], s[ct], 0, 0, 0);
            s[ct] = __builtin_amdgcn_mfma_f32_16x16x32_bf16(kf[1][ct], qf[1], s[ct], 0, 0, 0);
        }

        const bool diag = (kb == t);
        const int qg = t * 64 + wave * 16 + l15;
        bf16x4 pA[4];
#pragma unroll
        for (int ct = 0; ct < 4; ++ct) {
            float pv[4];
#pragma unroll
            for (int r = 0; r < 4; ++r) {
                const int key = kb * 64 + ct * 16 + quad * 4 + r;
                float sv = s[ct][r];
                if (diag && key > qg) sv = -INFINITY;
                pv[r] = fast_exp2(sv);
                lsum += pv[r];
            }
            pA[ct][0] = (short)f2bf(pv[0]); pA[ct][1] = (short)f2bf(pv[1]);
            pA[ct][2] = (short)f2bf(pv[2]); pA[ct][3] = (short)f2bf(pv[3]);
        }

        // O += P V (x16 MFMA; V frags from shared LDS, b64 2-way = free)
#pragma unroll
        for (int ct = 0; ct < 4; ++ct)
#pragma unroll
            for (int dt = 0; dt < 4; ++dt) {
                const bf16x4 vf = *(const bf16x4*)&sV[buf][(ct * 4 + dt) * 256 + lane * 4];
                o[dt] = mfma16_bf16(pA[ct], vf, o[dt]);
            }
    }

    // epilogue: full row-sum for q=l15 (reduce across quads), normalize, store
    float l = lsum;
    l += __shfl_xor(l, 16);
    l += __shfl_xor(l, 32);
    const float linv = 1.0f / l;                      // valid for q=l15
#pragma unroll
    for (int r = 0; r < 4; ++r) {
        const float inv = __shfl(linv, quad * 4 + r); // source lane's l15 == output q row
        const size_t row = (size_t)n * NCTX + t * 64 + wave * 16 + quad * 4 + r;
#pragma unroll
        for (int dt = 0; dt < 4; ++dt)
            out[row * D_MODEL + h * HD + dt * 16 + l15] = o[dt][r] * inv;
    }
}

extern "C" void kernel_launch(void* const* d_in, const int* in_sizes, int n_in,
                              void* d_out, int out_size, void* d_ws, size_t ws_size,
                              hipStream_t stream) {
    const float* x = (const float*)d_in[0];   // [2,2048,768]
    const float* W = (const float*)d_in[1];   // [2304,768]
    const float* b = (const float*)d_in[2];   // [2304]
    float* out = (float*)d_out;

    unsigned short* xb = (unsigned short*)d_ws;                    // 4096*768
    unsigned short* Wb = xb + (size_t)MROWS * D_MODEL;             // 2304*768
    unsigned short* Zq = Wb + (size_t)E3 * D_MODEL;                // 4096*768 (Q only)
    unsigned short* Kb = Zq + (size_t)MROWS * D_MODEL;             // 24*32*4096
    unsigned short* Vb = Kb + (size_t)NHTOT * 32 * 4096;           // 24*32*4096

    cast_bf16_kernel<<<dim3((MROWS * D_MODEL / 4) / 256), 256, 0, stream>>>(x, xb);
    cast_bf16_kernel<<<dim3((E3 * D_MODEL / 4) / 256), 256, 0, stream>>>(W, Wb);
    qkv_gemm<<<dim3(E3 / 96, MROWS / 128), 256, 0, stream>>>(xb, Wb, b, Zq, Kb, Vb);
    attn_kernel<<<dim3(NHTOT * (NCTX / 64)), 256, 0, stream>>>(Zq, Kb, Vb, out);
}

// Round 9
// 146.494 us; speedup vs baseline: 1.0619x; 1.0137x over previous
//
#include <hip/hip_runtime.h>
#include <stdint.h>

#define D_MODEL 768
#define E3      2304
#define NCTX    2048
#define NH      12
#define HD      64
#define MROWS   4096  // 2*2048
#define NHTOT   24    // 2*12

typedef __attribute__((ext_vector_type(8))) short short8;   // 8 bf16 — MFMA x32 A/B frag
typedef __attribute__((ext_vector_type(4))) short bf16x4;   // 4 bf16 — MFMA x16 A/B frag
typedef __attribute__((ext_vector_type(4))) float f32x4;    // MFMA C/D frag

typedef __attribute__((address_space(3))) uint32_t lds_u32;
typedef __attribute__((address_space(1))) uint32_t glob_u32;

__device__ __forceinline__ void async_copy16(const void* g, void* l) {
    __builtin_amdgcn_global_load_lds((const glob_u32*)(uintptr_t)g,
                                     (lds_u32*)(uint32_t)(uintptr_t)l, 16, 0, 0);
}

__device__ __forceinline__ unsigned short f2bf(float f) {  // RNE fp32->bf16
    uint32_t u = __builtin_bit_cast(uint32_t, f);
    u += 0x7fffu + ((u >> 16) & 1u);
    return (unsigned short)(u >> 16);
}

__device__ __forceinline__ float fast_exp2(float x) {
#if __has_builtin(__builtin_amdgcn_exp2f)
    return __builtin_amdgcn_exp2f(x);
#else
    return __expf(x * 0.6931471805599453f);
#endif
}

// x16 bf16 MFMA: device pass has the builtin; host pass lacks it (r6) — stub for parse.
__device__ __forceinline__ f32x4 mfma16_bf16(bf16x4 a, bf16x4 b, f32x4 c) {
#if defined(__HIP_DEVICE_COMPILE__)
    return __builtin_amdgcn_mfma_f32_16x16x16bf16_1k(a, b, c, 0, 0, 0);
#else
    (void)a; (void)b;
    return c;
#endif
}

// ---------------- cast fp32 -> bf16 ----------------
__global__ void cast_bf16_kernel(const float* __restrict__ in, unsigned short* __restrict__ out) {
    int i = blockIdx.x * blockDim.x + threadIdx.x;
    float4 v = ((const float4*)in)[i];
    ushort4 o;
    o.x = f2bf(v.x); o.y = f2bf(v.y); o.z = f2bf(v.z); o.w = f2bf(v.w);
    ((ushort4*)out)[i] = o;
}

// ---------------- QKV GEMM: r7 structure + XCD-aware swizzle ----------------
// k-major conflict-free LDS (r7): elem(R,k) = (R>>3)*512 + (k>>3)*64 + (R&7)*8 + (k&7)
// 1D grid 768, decode so xcd = id&7 hosts 4 contiguous row-tiles (512 A-rows, 0.8 MB)
// + all of B (3.5 MB) ≈ one 4 MB XCD L2 -> staging loads hit L2 after first touch
// instead of paying HBM latency at every barrier drain (r8 theory).
__global__ __launch_bounds__(256) void qkv_gemm(const unsigned short* __restrict__ A,
                                                const unsigned short* __restrict__ B,
                                                const float* __restrict__ bias,
                                                unsigned short* __restrict__ Zq,
                                                unsigned short* __restrict__ Kb,
                                                unsigned short* __restrict__ Vb) {
    __shared__ __attribute__((aligned(16))) unsigned short sA[128 * 64];
    __shared__ __attribute__((aligned(16))) unsigned short sB[96 * 64];

    const int tid  = threadIdx.x;
    const int wave = tid >> 6;
    const int lane = tid & 63;
    const int quad = lane >> 4;
    const int l15  = lane & 15;
    const int wm   = (wave >> 1) * 64;   // 0 or 64
    const int wn   = (wave & 1) * 48;    // 0 or 48

    // XCD swizzle: id&7 -> XCD (round-robin heuristic); each XCD gets row-tile band
    const int id   = blockIdx.x;
    const int by   = (id & 7) * 4 + ((id >> 3) & 3);  // 0..31 row tile
    const int bx   = id >> 5;                          // 0..23 col tile
    const int row0 = by * 128;
    const int col0 = bx * 96;

    const int srow   = lane & 7;         // row within 8-row region
    const int schunk = (lane >> 3) * 8;  // 8-elem k-chunk

    f32x4 acc[4][3] = {};

    for (int k0 = 0; k0 < D_MODEL; k0 += 64) {
        __syncthreads();
#pragma unroll
        for (int c = 0; c < 4; ++c) {    // A: 16 regions, 4 per wave
            const int reg = wave * 4 + c;
            async_copy16(A + (size_t)(row0 + reg * 8 + srow) * D_MODEL + k0 + schunk, &sA[reg * 512]);
        }
#pragma unroll
        for (int c = 0; c < 3; ++c) {    // B: 12 regions, 3 per wave
            const int reg = wave * 3 + c;
            async_copy16(B + (size_t)(col0 + reg * 8 + srow) * D_MODEL + k0 + schunk, &sB[reg * 512]);
        }
        __syncthreads();

#pragma unroll
        for (int ks = 0; ks < 2; ++ks) {
            const int qoff = (ks * 4 + quad) * 64 + (l15 & 7) * 8;
            short8 aF[4], bF[3];
#pragma unroll
            for (int i = 0; i < 4; ++i)
                aF[i] = *(const short8*)&sA[((wm >> 3) + i * 2 + (l15 >> 3)) * 512 + qoff];
#pragma unroll
            for (int j = 0; j < 3; ++j)
                bF[j] = *(const short8*)&sB[((wn >> 3) + j * 2 + (l15 >> 3)) * 512 + qoff];
#pragma unroll
            for (int i = 0; i < 4; ++i)
#pragma unroll
                for (int j = 0; j < 3; ++j)
                    acc[i][j] = __builtin_amdgcn_mfma_f32_16x16x32_bf16(aF[i], bF[j], acc[i][j], 0, 0, 0);
        }
    }

    // epilogue: C/D layout col=l15 (j dim), row=quad*4+reg (i dim)
    if (col0 < D_MODEL) {
        // ---- K -> Kb blocked: per (nh,kb): (((ks*4+ct)*4+quadd)*16 + key%16)*8 + e ----
#pragma unroll
        for (int j = 0; j < 3; ++j) {
            const int col = col0 + wn + j * 16 + l15;
            const float bv = bias[col];
            const int h = col >> 6, d = col & 63;
            const int ks = d >> 5, quadd = (d >> 3) & 3, e = d & 7;
#pragma unroll
            for (int i = 0; i < 4; ++i) {
                const int row = row0 + wm + i * 16 + quad * 4;
                const int n = row >> 11;
                const int key = row & (NCTX - 1);
                const int kb = key >> 6;
                const int ct = (key >> 4) & 3;
                const size_t base = ((size_t)((n * NH + h) * 32 + kb)) * 4096
                                  + (((ks * 4 + ct) * 4 + quadd) * 16) * 8 + e;
#pragma unroll
                for (int r = 0; r < 4; ++r)
                    Kb[base + (size_t)(quad * 4 + r) * 8] = f2bf(acc[i][j][r] + bv);
            }
        }
    } else if (col0 < 2 * D_MODEL) {
        // ---- Q -> Zq (scaled by log2e/sqrt(768)) ----
        const float zscale = 0.036084391824351615f * 1.4426950408889634f;
#pragma unroll
        for (int j = 0; j < 3; ++j) {
            const int colz = col0 + wn + j * 16 + l15;
            const float bv = bias[colz];
            const int col = colz - D_MODEL;
#pragma unroll
            for (int i = 0; i < 4; ++i) {
                const int row = row0 + wm + i * 16 + quad * 4;
#pragma unroll
                for (int r = 0; r < 4; ++r)
                    Zq[(size_t)(row + r) * D_MODEL + col] = f2bf((acc[i][j][r] + bv) * zscale);
            }
        }
    } else {
        // ---- V -> Vb blocked: per (nh,kb): (((ct*4+dt)*4+quadv)*16 + l15d)*4 + key%4 ----
#pragma unroll
        for (int j = 0; j < 3; ++j) {
            const int col = col0 + wn + j * 16 + l15;
            const float bv = bias[col];
            const int ch = col - 2 * D_MODEL;
            const int h = ch >> 6, d = ch & 63;
            const int dt = d >> 4, l15d = d & 15;
#pragma unroll
            for (int i = 0; i < 4; ++i) {
                const int row = row0 + wm + i * 16 + quad * 4;    // key base, %4==0
                const int n = row >> 11;
                const int key = row & (NCTX - 1);
                const int kb = key >> 6;
                const int ct = (key >> 4) & 3;
                ushort4 w4;
                w4.x = f2bf(acc[i][j][0] + bv);
                w4.y = f2bf(acc[i][j][1] + bv);
                w4.z = f2bf(acc[i][j][2] + bv);
                w4.w = f2bf(acc[i][j][3] + bv);
                *(ushort4*)&Vb[((size_t)((n * NH + h) * 32 + kb)) * 4096
                               + (((ct * 4 + dt) * 4 + quad) * 16 + l15d) * 4] = w4;
            }
        }
    }
}

// ---------------- flash attention: r5/r8 configuration (measured ~43 µs) ----------------
// Block = 4 waves = one q64-tile t of one (n,h); wave w owns q16 [t*64+w*16, +16).
// K AND V staged to LDS via global_load_lds (shared across waves), double-buffered,
// one __syncthreads per key-block. nh = b%24 groups 3 heads (3 MB K/V) per XCD.
// S^T = K*Q^T keeps P in x16-MFMA A-layout in registers. m fixed 0; l deferred.
__global__ __launch_bounds__(256) void attn_kernel(const unsigned short* __restrict__ Zq,
                                                   const unsigned short* __restrict__ Kb,
                                                   const unsigned short* __restrict__ Vb,
                                                   float* __restrict__ out) {
    __shared__ __attribute__((aligned(16))) unsigned short sK[2][4096];
    __shared__ __attribute__((aligned(16))) unsigned short sV[2][4096];

    const int tid  = threadIdx.x;
    const int wave = tid >> 6;
    const int lane = tid & 63;
    const int quad = lane >> 4;
    const int l15  = lane & 15;
    const int b    = blockIdx.x;
    const int nh   = b % NHTOT;
    const int t    = (NCTX / 64 - 1) - b / NHTOT;    // heavy-first
    const int n    = nh / NH;
    const int h    = nh - n * NH;

    const unsigned short* KbP = Kb + (size_t)(nh * 32) * 4096;
    const unsigned short* VbP = Vb + (size_t)(nh * 32) * 4096;

    // Q B-frags: lane holds Q[q = t*64+wave*16+l15][d = ks*32+quad*8..+7]
    const unsigned short* Qp = Zq + (size_t)(n * NCTX + t * 64 + wave * 16) * D_MODEL + h * HD;
    short8 qf[2];
#pragma unroll
    for (int ks = 0; ks < 2; ++ks)
        qf[ks] = *(const short8*)&Qp[(size_t)l15 * D_MODEL + ks * 32 + quad * 8];

    f32x4 o[4] = {};   // [dt]: O[q=quad*4+r][d=dt*16+l15]
    float lsum = 0.0f; // partial row-sum for q=l15

    // prologue: stage K+V (kb=0); 16 KB / 4 waves = 4 instrs/wave
#pragma unroll
    for (int c = 0; c < 2; ++c) {
        const int off = wave * 1024 + c * 512;
        async_copy16(KbP + off + lane * 8, &sK[0][off]);
        async_copy16(VbP + off + lane * 8, &sV[0][off]);
    }

    for (int kb = 0; kb <= t; ++kb) {
        const int buf = kb & 1;
        __syncthreads();                               // drains staging of kb; frees buf^1
        if (kb < t) {
#pragma unroll
            for (int c = 0; c < 2; ++c) {
                const int off = wave * 1024 + c * 512;
                async_copy16(KbP + (size_t)(kb + 1) * 4096 + off + lane * 8, &sK[buf ^ 1][off]);
                async_copy16(VbP + (size_t)(kb + 1) * 4096 + off + lane * 8, &sV[buf ^ 1][off]);
            }
        }

        // K A-frags from LDS (lane-linear, conflict-free)
        short8 kf[2][4];
#pragma unroll
        for (int ks = 0; ks < 2; ++ks)
#pragma unroll
            for (int ct = 0; ct < 4; ++ct)
                kf[ks][ct] = *(const short8*)&sK[buf][(ks * 4 + ct) * 512 + lane * 8];

        // S^T = K Q^T: lane holds S[q=l15][key = kb*64 + ct*16 + quad*4 + r]
        f32x4 s[4] = {};
#pragma unroll
        for (int ct = 0; ct < 4; ++ct) {
            s[ct] = __builtin_amdgcn_mfma_f32_16x16x32_bf16(kf[0][ct], qf[0], s[ct], 0, 0, 0);
            s[ct] = __builtin_amdgcn_mfma_f32_16x16x32_bf16(kf[1][ct], qf[1], s[ct], 0, 0, 0);
        }

        const bool diag = (kb == t);
        const int qg = t * 64 + wave * 16 + l15;
        bf16x4 pA[4];
#pragma unroll
        for (int ct = 0; ct < 4; ++ct) {
            float pv[4];
#pragma unroll
            for (int r = 0; r < 4; ++r) {
                const int key = kb * 64 + ct * 16 + quad * 4 + r;
                float sv = s[ct][r];
                if (diag && key > qg) sv = -INFINITY;
                pv[r] = fast_exp2(sv);
                lsum += pv[r];
            }
            pA[ct][0] = (short)f2bf(pv[0]); pA[ct][1] = (short)f2bf(pv[1]);
            pA[ct][2] = (short)f2bf(pv[2]); pA[ct][3] = (short)f2bf(pv[3]);
        }

        // O += P V (x16 MFMA; V frags from shared LDS, b64 2-way = free)
#pragma unroll
        for (int ct = 0; ct < 4; ++ct)
#pragma unroll
            for (int dt = 0; dt < 4; ++dt) {
                const bf16x4 vf = *(const bf16x4*)&sV[buf][(ct * 4 + dt) * 256 + lane * 4];
                o[dt] = mfma16_bf16(pA[ct], vf, o[dt]);
            }
    }

    // epilogue: full row-sum for q=l15 (reduce across quads), normalize, store
    float l = lsum;
    l += __shfl_xor(l, 16);
    l += __shfl_xor(l, 32);
    const float linv = 1.0f / l;                      // valid for q=l15
#pragma unroll
    for (int r = 0; r < 4; ++r) {
        const float inv = __shfl(linv, quad * 4 + r); // source lane's l15 == output q row
        const size_t row = (size_t)n * NCTX + t * 64 + wave * 16 + quad * 4 + r;
#pragma unroll
        for (int dt = 0; dt < 4; ++dt)
            out[row * D_MODEL + h * HD + dt * 16 + l15] = o[dt][r] * inv;
    }
}

extern "C" void kernel_launch(void* const* d_in, const int* in_sizes, int n_in,
                              void* d_out, int out_size, void* d_ws, size_t ws_size,
                              hipStream_t stream) {
    const float* x = (const float*)d_in[0];   // [2,2048,768]
    const float* W = (const float*)d_in[1];   // [2304,768]
    const float* b = (const float*)d_in[2];   // [2304]
    float* out = (float*)d_out;

    unsigned short* xb = (unsigned short*)d_ws;                    // 4096*768
    unsigned short* Wb = xb + (size_t)MROWS * D_MODEL;             // 2304*768
    unsigned short* Zq = Wb + (size_t)E3 * D_MODEL;                // 4096*768 (Q only)
    unsigned short* Kb = Zq + (size_t)MROWS * D_MODEL;             // 24*32*4096
    unsigned short* Vb = Kb + (size_t)NHTOT * 32 * 4096;           // 24*32*4096

    cast_bf16_kernel<<<dim3((MROWS * D_MODEL / 4) / 256), 256, 0, stream>>>(x, xb);
    cast_bf16_kernel<<<dim3((E3 * D_MODEL / 4) / 256), 256, 0, stream>>>(W, Wb);
    qkv_gemm<<<dim3(768), 256, 0, stream>>>(xb, Wb, b, Zq, Kb, Vb);
    attn_kernel<<<dim3(NHTOT * (NCTX / 64)), 256, 0, stream>>>(Zq, Kb, Vb, out);
}